// Round 10
// baseline (282.615 us; speedup 1.0000x reference)
//
#include <hip/hip_runtime.h>
#include <hip/hip_fp16.h>

#define M_TOK 512
#define N_OUT 11008
#define K_IN  4096
// tile: BM=128, BN=64, BK=64; 256 threads = 4 waves (2x2), wave-tile 64m x 32n
// B decoded DIRECTLY into register fragments (no LDS, no barrier for B).
//   qweight layout: ONE byte per int32 (2 k-values); 2048 int32 per n-row.
//   Per-lane fragment (8 k) = one int4 = 4 int32 = 4 dq_pairs.  [R9 bugfix]
// A double-buffered in LDS via gload_lds, prefetched 1 iter ahead; ONE barrier/iter.

typedef _Float16 f16x8 __attribute__((ext_vector_type(8)));
typedef _Float16 f16x2 __attribute__((ext_vector_type(2)));
typedef float    f32x4 __attribute__((ext_vector_type(4)));
typedef unsigned int u32x4 __attribute__((ext_vector_type(4)));

// ---------------- prep: x fp32 -> f16 ----------------
__global__ __launch_bounds__(256) void cvt_x_kernel(const float* __restrict__ x,
                                                    _Float16* __restrict__ xh) {
    int i = (blockIdx.x * 256 + threadIdx.x) * 8;
    float4 a = *(const float4*)(x + i);
    float4 b = *(const float4*)(x + i + 4);
    f16x8 v;
    v[0] = (_Float16)a.x; v[1] = (_Float16)a.y; v[2] = (_Float16)a.z; v[3] = (_Float16)a.w;
    v[4] = (_Float16)b.x; v[5] = (_Float16)b.y; v[6] = (_Float16)b.z; v[7] = (_Float16)b.w;
    *(f16x8*)(xh + i) = v;
}

// async global->LDS, 16B per lane (dest = wave-uniform base + lane*16)
__device__ __forceinline__ void gload_lds16(const void* g, void* l) {
    __builtin_amdgcn_global_load_lds(
        (const __attribute__((address_space(1))) void*)g,
        (__attribute__((address_space(3))) void*)l,
        16, 0, 0);
}

// dequant one byte-in-int32 (low 8 bits) -> packed f16 pair {(lo-z)*s, (hi-z)*s}
__device__ __forceinline__ unsigned int dq_pair(unsigned int b, f16x2 fz2, f16x2 ss2) {
    unsigned int u = (b & 15u) |
                     ((b << 12) & 0xF0000u) |
                     0x64006400u;                       // {1024+lo, 1024+hi} as f16x2
    f16x2 h = __builtin_bit_cast(f16x2, u);
    f16x2 w = (h - fz2) * ss2;                          // exact sub (Sterbenz), one f16 rounding
    return __builtin_bit_cast(unsigned int, w);
}

__global__ __launch_bounds__(256, 3)
void gemm_w4_kernel(const int* __restrict__ qw,      // (N, 32, 64) int32, 1 byte each
                    const float* __restrict__ scales, // flat N*32
                    const int* __restrict__ qz,       // flat N*32/2 bytes (nibble pairs)
                    const _Float16* __restrict__ xh,  // (M, K) f16
                    float* __restrict__ out) {        // (M, N) f32, direct write
    __shared__ __align__(16) char As[2][16384];   // dbuf: 128 m-rows x 64 k x 2B, XOR-swizzled

    // XCD-chunked bijective swizzle: 688 = 8*86; mx-fastest -> 4 same-ny qweight
    // sharers consecutive on one XCD -> L2 reuse.
    const int hw  = blockIdx.x;
    const int logical = (hw & 7) * 86 + (hw >> 3);
    const int mx = logical & 3;
    const int ny = logical >> 2;        // 0..171

    const int n0 = ny * 64;
    const int m0 = mx * 128;

    const int tid  = threadIdx.x;
    const int lane = tid & 63;
    const int wid  = tid >> 6;
    const int wm   = wid >> 1;      // wave m index (0..1), 64 rows
    const int wn   = wid & 1;       // wave n index (0..1), 32 cols
    const int r16  = lane & 15;
    const int g4   = lane >> 4;

    // ---- A staging sources (pre-swizzled global, linear LDS dest) ----
    const char* xbytes = (const char*)xh;
    const char* asrc[4];
#pragma unroll
    for (int i = 0; i < 4; ++i) {
        int row = (tid >> 3) + i * 32;
        int cb  = (tid & 7) * 16;
        int cbl = cb ^ ((row & 7) << 4);
        asrc[i] = xbytes + (size_t)(m0 + row) * (K_IN * 2) + cbl;
    }

    // ---- A fragment LDS byte-offsets (within one buffer), swizzled read ----
    unsigned aoff[4][2];
#pragma unroll
    for (int mi = 0; mi < 4; ++mi) {
        int row = wm * 64 + mi * 16 + r16;
#pragma unroll
        for (int kh = 0; kh < 2; ++kh)
            aoff[mi][kh] = row * 128 + (((kh << 6) | (g4 << 4)) ^ ((row & 7) << 4));
    }

    // ---- B: per-lane register-fragment decode; rows for ni=0,1 ----
    // Row stride = 2048 int32 = 512 int4. Fragment (it,kh) k-range [it*64+kh*32+g4*8, +8)
    // -> int32 j0 = it*32+kh*16+g4*4 -> int4 index it*8+kh*4+g4.
    const int nrow0 = n0 + wn * 32 + r16;
    const int nrow1 = nrow0 + 16;
    const int4* qrow0 = (const int4*)qw + (size_t)nrow0 * 512;
    const int4* qrow1 = (const int4*)qw + (size_t)nrow1 * 512;

    // ---- prologue: scales/zeros group 0, qv(it=0), stage A(0) ----
    float s_pf0 = scales[nrow0 * 32];
    float s_pf1 = scales[nrow1 * 32];
    int   z_pf0 = qz[nrow0 * 16] & 15;          // f = nrow*32 -> qz[f>>1], nibble 0
    int   z_pf1 = qz[nrow1 * 16] & 15;

    int4 qv_cur[2][2], qv_nxt[2][2];
#pragma unroll
    for (int kh = 0; kh < 2; ++kh) {
        qv_cur[0][kh] = qrow0[kh * 4 + g4];
        qv_cur[1][kh] = qrow1[kh * 4 + g4];
    }
#pragma unroll
    for (int i = 0; i < 4; ++i)
        gload_lds16(asrc[i], &As[0][(wid * 64 + i * 256) * 16]);

    f16x2 ss2[2], fz2[2];
    {
        _Float16 sh0 = (_Float16)s_pf0, sh1 = (_Float16)s_pf1;
        _Float16 fz0 = (_Float16)(float)(1024 + z_pf0), fz1 = (_Float16)(float)(1024 + z_pf1);
        ss2[0] = (f16x2){sh0, sh0}; ss2[1] = (f16x2){sh1, sh1};
        fz2[0] = (f16x2){fz0, fz0}; fz2[1] = (f16x2){fz1, fz1};
    }

    f32x4 acc[4][2];
#pragma unroll
    for (int mi = 0; mi < 4; ++mi)
#pragma unroll
        for (int ni = 0; ni < 2; ++ni)
            acc[mi][ni] = (f32x4){0.f, 0.f, 0.f, 0.f};

    __syncthreads();   // A(0) staged (vmcnt drain) — prologue only

#pragma unroll 2
    for (int it = 0; it < 64; ++it) {
        const int buf = it & 1;

        // prefetch next iteration's A tile + qweight (1 full iter of latency hiding)
        if (it < 63) {
#pragma unroll
            for (int i = 0; i < 4; ++i)
                gload_lds16(asrc[i] + (it + 1) * 128, &As[buf ^ 1][(wid * 64 + i * 256) * 16]);
#pragma unroll
            for (int kh = 0; kh < 2; ++kh) {
                qv_nxt[0][kh] = qrow0[(it + 1) * 8 + kh * 4 + g4];
                qv_nxt[1][kh] = qrow1[(it + 1) * 8 + kh * 4 + g4];
            }
        }
        // prefetch next group's scale/zero (every 2nd iter)
        if (((it & 1) == 0) && (it < 62)) {
            const int g = (it >> 1) + 1;
            const int f0 = nrow0 * 32 + g, f1 = nrow1 * 32 + g;
            s_pf0 = scales[f0];
            s_pf1 = scales[f1];
            z_pf0 = (qz[f0 >> 1] >> ((f0 & 1) * 4)) & 15;
            z_pf1 = (qz[f1 >> 1] >> ((f1 & 1) * 4)) & 15;
        }

        // decode B fragments in registers: 4 int32 (1 byte each) -> 8 f16
        f16x8 bf[2][2];
#pragma unroll
        for (int ni = 0; ni < 2; ++ni) {
#pragma unroll
            for (int kh = 0; kh < 2; ++kh) {
                const int4 v = qv_cur[ni][kh];
                u32x4 t;
                t.x = dq_pair((unsigned)v.x, fz2[ni], ss2[ni]);
                t.y = dq_pair((unsigned)v.y, fz2[ni], ss2[ni]);
                t.z = dq_pair((unsigned)v.z, fz2[ni], ss2[ni]);
                t.w = dq_pair((unsigned)v.w, fz2[ni], ss2[ni]);
                bf[ni][kh] = __builtin_bit_cast(f16x8, t);
            }
        }

        // A fragments from LDS + MFMA
#pragma unroll
        for (int kh = 0; kh < 2; ++kh) {
            f16x8 af[4];
#pragma unroll
            for (int mi = 0; mi < 4; ++mi)
                af[mi] = *(const f16x8*)(&As[buf][0] + aoff[mi][kh]);
#pragma unroll
            for (int mi = 0; mi < 4; ++mi)
#pragma unroll
                for (int ni = 0; ni < 2; ++ni)
                    acc[mi][ni] = __builtin_amdgcn_mfma_f32_16x16x32_f16(
                        af[mi], bf[ni][kh], acc[mi][ni], 0, 0, 0);
        }

        __syncthreads();   // ONE barrier: drains next-tile gload_lds; fences LDS reuse

        if (it < 63) {
#pragma unroll
            for (int kh = 0; kh < 2; ++kh) {
                qv_cur[0][kh] = qv_nxt[0][kh];
                qv_cur[1][kh] = qv_nxt[1][kh];
            }
        }
        if (((it & 1) == 1) && (it < 63)) {   // convert prefetched (s,z) for group (it>>1)+1
            _Float16 sh0 = (_Float16)s_pf0, sh1 = (_Float16)s_pf1;
            _Float16 fz0 = (_Float16)(float)(1024 + z_pf0), fz1 = (_Float16)(float)(1024 + z_pf1);
            ss2[0] = (f16x2){sh0, sh0}; ss2[1] = (f16x2){sh1, sh1};
            fz2[0] = (f16x2){fz0, fz0}; fz2[1] = (f16x2){fz1, fz1};
        }
    }

    // epilogue: D col = lane&15, row = (lane>>4)*4 + reg; direct coalesced stores
#pragma unroll
    for (int mi = 0; mi < 4; ++mi) {
#pragma unroll
        for (int ni = 0; ni < 2; ++ni) {
            const int col   = n0 + wn * 32 + ni * 16 + r16;
            const int rbase = m0 + wm * 64 + mi * 16 + g4 * 4;
            f32x4 v = acc[mi][ni];
#pragma unroll
            for (int r = 0; r < 4; ++r)
                out[(size_t)(rbase + r) * N_OUT + col] = v[r];
        }
    }
}

extern "C" void kernel_launch(void* const* d_in, const int* in_sizes, int n_in,
                              void* d_out, int out_size, void* d_ws, size_t ws_size,
                              hipStream_t stream) {
    const float* x  = (const float*)d_in[0];
    const int*   qw = (const int*)d_in[1];
    const float* sc = (const float*)d_in[2];
    const int*   qz = (const int*)d_in[3];
    _Float16*    xh = (_Float16*)d_ws;     // 512*4096*2 = 4 MB scratch
    float*       out = (float*)d_out;

    // x -> f16 (2M elements, 8 per thread)
    cvt_x_kernel<<<dim3((M_TOK * K_IN) / (256 * 8)), 256, 0, stream>>>(x, xh);

    // fused dequant GEMM: 172 x 4 = 688 blocks, XCD-swizzled, B-in-regs, 1 barrier/iter
    gemm_w4_kernel<<<dim3(688), 256, 0, stream>>>(qw, sc, qz, xh, out);
}